// Round 11
// baseline (544.819 us; speedup 1.0000x reference)
//
#include <hip/hip_runtime.h>
#include <hip/hip_bf16.h>
#include <cstdint>

typedef short bf16x8 __attribute__((ext_vector_type(8)));
typedef float f32x4 __attribute__((ext_vector_type(4)));

__device__ __forceinline__ float lrelu_f(float y) { return y >= 0.f ? y : 0.2f * y; }
__device__ __forceinline__ float b2f(unsigned short u) {
    union { unsigned int i; float f; } v; v.i = ((unsigned int)u) << 16; return v.f;
}
__device__ __forceinline__ unsigned short f2b(float f) {
    union { unsigned int i; float f; } v; v.f = f;
    unsigned int r = v.i + 0x7FFFu + ((v.i >> 16) & 1u);
    return (unsigned short)(r >> 16);
}

// ---------------------------------------------------------------------------
// Fused prep: input NCDHW->CL bf16 repack (blocks 0..131071) + all-weight
// repack (blocks 131072..162079).
// ---------------------------------------------------------------------------
__global__ __launch_bounds__(256) void prep_k(
    const float* __restrict__ x, unsigned short* __restrict__ xc,
    const float* __restrict__ w1, const float* __restrict__ w2,
    const float* __restrict__ w3, const float* __restrict__ w4,
    const float* __restrict__ w_off, const float* __restrict__ w5,
    const float* __restrict__ w6, unsigned short* __restrict__ wp)
{
    int bid = blockIdx.x;
    if (bid < 131072) {
        int i = bid * 256 + threadIdx.x;      // 33554432 threads
        int c = i & 3, w = (i >> 2) & 127, h = (i >> 9) & 127, d = (i >> 16) & 7, b = i >> 19;
        float v = (c < 3) ? x[(((size_t)b * 3 + c) * 8 + d) * 16384 + h * 128 + w] : 0.f;
        xc[i] = f2b(v);
        return;
    }
    long i = (long)(bid - 131072) * 256 + threadIdx.x;   // 7,938,048 threads
    const float* src; int Cin, Tap, Cip; long rel;
    if (i < 8192)         { src = w1;    Cin = 3;   Tap = 64; Cip = 4;   rel = i; }
    else if (i < 73728)   { src = w2;    Cin = 32;  Tap = 32; Cip = 32;  rel = i - 8192; }
    else if (i < 335872)  { src = w3;    Cin = 64;  Tap = 32; Cip = 64;  rel = i - 73728; }
    else if (i < 860160)  { src = w4;    Cin = 128; Tap = 16; Cip = 128; rel = i - 335872; }
    else if (i < 1646592) { src = w_off; Cin = 256; Tap = 16; Cip = 256; rel = i - 860160; }
    else if (i < 3743744) { src = w5;    Cin = 256; Tap = 16; Cip = 256; rel = i - 1646592; }
    else                  { src = w6;    Cin = 512; Tap = 16; Cip = 512; rel = i - 3743744; }
    int c = (int)(rel % Cip);
    long t1 = rel / Cip;
    int t = (int)(t1 % Tap);
    long o = t1 / Tap;
    wp[i] = (c < Cin) ? f2b(src[((size_t)o * Cin + c) * Tap + t]) : (unsigned short)0;
}

// ---------------------------------------------------------------------------
// Implicit-GEMM MFMA kernel. C[M][N] = A[M][K] * Bw[N][K]^T, bf16 in, fp32 acc.
// Tile TM x BN (threads = TM*2), K-step 64 (two 32-chunks per barrier pair).
// Simple stage->sync->MFMA->sync loop: measured best (r7/r10); r8 (LDS dbuf)
// hit the occupancy cliff, r9 (reg-staged) spilled to scratch. Do not pipeline.
// XCD-chunked blockIdx.x swizzle (T1) applied when gridDim.x % 8 == 0.
// AMODE 0: plain row-major bf16 [M][K]
// AMODE 1: CL im2col, K order [tap][c], Ci%32==0, masked borders; split-K ok
// AMODE 2: conv1: 4x4x4, Cip=4, K order [tap][c4], masked
// EPI 0: bf16; EPI 1: fp32; EPI 2: fp32 atomicAdd; EPI 3: lrelu+bf16;
// EPI 4: bf16 + per-channel sum/sumsq; EPI 5: lrelu+bf16 + fp32 NCDHW float4
// ---------------------------------------------------------------------------
template<int TM, int BN, int AMODE, int EPI>
__global__ __launch_bounds__(TM * 2) void igemm(
    const unsigned short* __restrict__ A, const unsigned short* __restrict__ Bw,
    void* __restrict__ Cout, float* __restrict__ sums,
    int M, int N, int K, int klen,
    int Ci, int Di, int Hi, int Wi,
    int kd, int kh, int kw,
    int sd, int sh_, int sw_, int pd, int ph_, int pw_,
    int Do, int Ho, int Wo)
{
    constexpr int NT = TM * 2;
    constexpr int NF = BN / 32;
    constexpr int WN = 16 * NF;
    constexpr int NBU = (BN * 4 + NT - 1) / NT;
    constexpr int NAU = (AMODE == 2) ? 4 : 2;
    constexpr int AH = 4 * TM * 8;         // shorts per As k-chunk buffer
    constexpr int BH = 4 * BN * 8;
    __shared__ __align__(16) unsigned short As[2][4][TM][8];
    __shared__ __align__(16) unsigned short Bs[2][4][BN][8];
    __shared__ float redbuf[(EPI == 4) ? 2 * BN : 1];
    const int tid = threadIdx.x;
    int bx = blockIdx.x;
    if ((gridDim.x & 7) == 0)              // XCD-chunked swizzle (bijective)
        bx = (bx & 7) * (gridDim.x >> 3) + (bx >> 3);
    const int m0 = bx * TM;
    const int n0 = blockIdx.y * BN;
    const int k0 = blockIdx.z * klen;
    const int kend = min(K, k0 + klen);
    unsigned short* const As0 = &As[0][0][0][0];
    unsigned short* const Bs0 = &Bs[0][0][0][0];

    // B staging precompute
    size_t bsrc[NBU];
    int boff[NBU];
#pragma unroll
    for (int i = 0; i < NBU; ++i) {
        int u = tid + i * NT;
        int row = u >> 2, s = u & 3;
        if (BN * 4 >= NT || u < BN * 4) {
            bsrc[i] = (size_t)(n0 + row) * K + s * 8;
            boff[i] = (s * BN + row) * 8;
        }
    }

    // A staging precompute
    size_t asz[2];
    int asrc[NAU];
    unsigned long long amask[NAU];
    int aoff[NAU];

    if constexpr (AMODE == 0) {
#pragma unroll
        for (int i = 0; i < 2; ++i) {
            int u = tid + i * NT;
            int r = u >> 2, s = u & 3;
            asz[i] = (size_t)(m0 + r) * K + s * 8;
            aoff[i] = (s * TM + r) * 8;
        }
    } else {
#pragma unroll
        for (int i = 0; i < NAU; ++i) {
            int u = tid + i * NT;
            int r = (AMODE == 2) ? (u >> 3) : (u >> 2);
            int m = m0 + r;
            int ow = m % Wo; int t1 = m / Wo;
            int oh = t1 % Ho; t1 /= Ho;
            int od = t1 % Do; int b = t1 / Do;
            int id0 = od * sd - pd, ih0 = oh * sh_ - ph_, iw0 = ow * sw_ - pw_;
            unsigned long long xm = 0ull, yx = 0ull, mask = 0ull;
            for (int p = 0; p < kw; ++p) if ((unsigned)(iw0 + p) < (unsigned)Wi) xm |= 1ull << p;
            for (int p = 0; p < kh; ++p) if ((unsigned)(ih0 + p) < (unsigned)Hi) yx |= xm << (p * kw);
            for (int p = 0; p < kd; ++p) if ((unsigned)(id0 + p) < (unsigned)Di) mask |= yx << (p * kh * kw);
            amask[i] = mask;
            int bsp = ((b * Di + id0) * Hi + ih0) * Wi + iw0;
            if constexpr (AMODE == 1) {
                int s = u & 3;
                asrc[i] = bsp * Ci + s * 8;
                aoff[i] = (s * TM + r) * 8;
            } else {
                int j = u & 7;
                asrc[i] = (bsp + (j >> 2) * Wi + (j & 3)) * 4;
                aoff[i] = ((j >> 1) * TM + r) * 8 + (j & 1) * 4;
            }
        }
    }

    f32x4 acc[4][NF];
#pragma unroll
    for (int i = 0; i < 4; ++i)
#pragma unroll
        for (int j = 0; j < NF; ++j) acc[i][j] = (f32x4){0.f, 0.f, 0.f, 0.f};

    const int lane = tid & 63, wv = tid >> 6;
    const int wm = wv >> 1, wn = wv & 1;
    const int kg = lane >> 4, fr = lane & 15;

    // uniform k-walk state (AMODE 1), initialized from k0 for split-K
    int c0 = 0, kx = 0, ky = 0, tap = 0, doff = 0;
    if constexpr (AMODE == 1) {
        c0 = k0 % Ci;
        tap = k0 / Ci;
        kx = tap % kw;
        int t2 = tap / kw;
        ky = t2 % kh;
        int kz = t2 / kh;
        doff = (kz * Hi + ky) * Wi + kx;
    }
    auto advance = [&]() {
        c0 += 32;
        if (c0 >= Ci) {
            c0 = 0; ++tap; ++kx; ++doff;
            if (kx == kw) {
                kx = 0; doff += Wi - kw; ++ky;
                if (ky == kh) { ky = 0; doff += (Hi - kh) * Wi; }
            }
        }
    };

    for (int k = k0; k < kend; k += 64) {
        // ---- B stage (two chunks)
#pragma unroll
        for (int i = 0; i < NBU; ++i)
            if (BN * 4 >= NT || tid + i * NT < BN * 4) {
                uint4 v0 = *(const uint4*)&Bw[bsrc[i] + k];
                uint4 v1 = *(const uint4*)&Bw[bsrc[i] + k + 32];
                *(uint4*)(Bs0 + boff[i]) = v0;
                *(uint4*)(Bs0 + BH + boff[i]) = v1;
            }
        // ---- A stage (two chunks)
        if constexpr (AMODE == 0) {
#pragma unroll
            for (int i = 0; i < 2; ++i) {
                uint4 v0 = *(const uint4*)&A[asz[i] + k];
                uint4 v1 = *(const uint4*)&A[asz[i] + k + 32];
                *(uint4*)(As0 + aoff[i]) = v0;
                *(uint4*)(As0 + AH + aoff[i]) = v1;
            }
        } else if constexpr (AMODE == 1) {
            int t0 = tap, d0 = doff * Ci + c0;
            advance();
            int t1 = tap, d1 = doff * Ci + c0;
            advance();
#pragma unroll
            for (int i = 0; i < 2; ++i) {
                uint4 v0 = {0u, 0u, 0u, 0u}, v1 = {0u, 0u, 0u, 0u};
                if ((amask[i] >> t0) & 1ull) v0 = *(const uint4*)&A[(size_t)(asrc[i] + d0)];
                if ((amask[i] >> t1) & 1ull) v1 = *(const uint4*)&A[(size_t)(asrc[i] + d1)];
                *(uint4*)(As0 + aoff[i]) = v0;
                *(uint4*)(As0 + AH + aoff[i]) = v1;
            }
        } else {
            int kz = k >> 6;
            int U0 = kz * (Hi * Wi) * 4;
            int U1 = U0 + 2 * Wi * 4;
            int tap0 = k >> 2;
#pragma unroll
            for (int i = 0; i < 4; ++i) {
                int j = (tid + i * NT) & 7;
                uint2 v0 = {0u, 0u}, v1 = {0u, 0u};
                if ((amask[i] >> (tap0 + j)) & 1ull)
                    v0 = *(const uint2*)&A[(size_t)(asrc[i] + U0)];
                if ((amask[i] >> (tap0 + 8 + j)) & 1ull)
                    v1 = *(const uint2*)&A[(size_t)(asrc[i] + U1)];
                *(uint2*)(As0 + aoff[i]) = v0;
                *(uint2*)(As0 + AH + aoff[i]) = v1;
            }
        }
        __syncthreads();
#pragma unroll
        for (int kb = 0; kb < 2; ++kb) {
            bf16x8 af[4], bfr[NF];
#pragma unroll
            for (int mi = 0; mi < 4; ++mi)
                af[mi] = *(const bf16x8*)&As[kb][kg][wm * 64 + mi * 16 + fr][0];
#pragma unroll
            for (int ni = 0; ni < NF; ++ni)
                bfr[ni] = *(const bf16x8*)&Bs[kb][kg][wn * WN + ni * 16 + fr][0];
#pragma unroll
            for (int mi = 0; mi < 4; ++mi)
#pragma unroll
                for (int ni = 0; ni < NF; ++ni)
                    acc[mi][ni] = __builtin_amdgcn_mfma_f32_16x16x32_bf16(af[mi], bfr[ni], acc[mi][ni], 0, 0, 0);
        }
        __syncthreads();
    }

    // ---- epilogue: D row=(lane>>4)*4+reg, col=lane&15
    if constexpr (EPI == 4) {
        for (int j = tid; j < 2 * BN; j += NT) redbuf[j] = 0.f;
        __syncthreads();
    }
    const int rb = m0 + wm * 64 + (lane >> 4) * 4;
    const int cb = n0 + wn * WN + fr;
    float p1[NF], p2[NF];
    if constexpr (EPI == 4) {
#pragma unroll
        for (int ni = 0; ni < NF; ++ni) { p1[ni] = 0.f; p2[ni] = 0.f; }
    }
#pragma unroll
    for (int mi = 0; mi < 4; ++mi)
#pragma unroll
        for (int rg = 0; rg < 4; ++rg) {
            size_t rowbase = (size_t)(rb + mi * 16 + rg) * N;
#pragma unroll
            for (int ni = 0; ni < NF; ++ni) {
                size_t idx = rowbase + cb + ni * 16;
                float vv = acc[mi][ni][rg];
                if constexpr (EPI == 0) ((unsigned short*)Cout)[idx] = f2b(vv);
                else if constexpr (EPI == 1) ((float*)Cout)[idx] = vv;
                else if constexpr (EPI == 2) atomicAdd((float*)Cout + idx, vv);
                else if constexpr (EPI == 3 || EPI == 5) ((unsigned short*)Cout)[idx] = f2b(lrelu_f(vv));
                else {
                    ((unsigned short*)Cout)[idx] = f2b(vv);
                    p1[ni] += vv; p2[ni] += vv * vv;
                }
            }
        }
    if constexpr (EPI == 4) {
#pragma unroll
        for (int ni = 0; ni < NF; ++ni) {
            int cl = wn * WN + ni * 16 + fr;
            atomicAdd(&redbuf[cl], p1[ni]);
            atomicAdd(&redbuf[BN + cl], p2[ni]);
        }
        __syncthreads();
        for (int j = tid; j < 2 * BN; j += NT) {
            int gcol = (j < BN) ? (n0 + j) : (N + n0 + j - BN);
            atomicAdd(&sums[gcol], redbuf[j]);
        }
    }
    if constexpr (EPI == 5) {
        // direct fp32 NCDHW store (conv1 geometry: C=32, S=16384)
#pragma unroll
        for (int mi = 0; mi < 4; ++mi) {
            int mr = rb + mi * 16;
            int b = mr >> 14, ssp = mr & 16383;
            float4 f;
            f.x = lrelu_f(acc[mi][0][0]);
            f.y = lrelu_f(acc[mi][0][1]);
            f.z = lrelu_f(acc[mi][0][2]);
            f.w = lrelu_f(acc[mi][0][3]);
            *(float4*)&sums[((size_t)(b * 32 + cb)) * 16384 + ssp] = f;
        }
    }
}

// ---------------------------------------------------------------------------
// Fused fp32->bf16 convert + BN partial sums (for split-K fp32 outputs).
// ---------------------------------------------------------------------------
__global__ __launch_bounds__(256) void f2b_sums(const float* __restrict__ in,
                                                unsigned short* __restrict__ o,
                                                float* __restrict__ sums,
                                                long totalSlots, int C)
{
    const int tid = threadIdx.x;
    long gid = (long)blockIdx.x * 256 + tid;
    long stride = (long)gridDim.x * 256;     // stride*8 % C == 0 required
    float s1[8], s2[8];
#pragma unroll
    for (int j = 0; j < 8; ++j) { s1[j] = 0.f; s2[j] = 0.f; }
    for (long s = gid; s < totalSlots; s += stride) {
        float4 a = *(const float4*)&in[s * 8];
        float4 b = *(const float4*)&in[s * 8 + 4];
        float f[8] = {a.x, a.y, a.z, a.w, b.x, b.y, b.z, b.w};
        unsigned short u[8];
#pragma unroll
        for (int j = 0; j < 8; ++j) { u[j] = f2b(f[j]); s1[j] += f[j]; s2[j] += f[j] * f[j]; }
        *(uint4*)&o[s * 8] = *(uint4*)u;
    }
    __shared__ float r1[2048], r2[2048];
#pragma unroll
    for (int j = 0; j < 8; ++j) { r1[tid * 8 + j] = s1[j]; r2[tid * 8 + j] = s2[j]; }
    __syncthreads();
    int G = C >> 3;
    for (int c = tid; c < C; c += 256) {
        int grp = c >> 3, j = c & 7;
        float a = 0.f, b = 0.f;
        for (int th = grp; th < 256; th += G) { a += r1[th * 8 + j]; b += r2[th * 8 + j]; }
        atomicAdd(&sums[c], a);
        atomicAdd(&sums[C + c], b);
    }
}

// ---------------------------------------------------------------------------
// BN finalize (from sums slice) + apply + lrelu + NCDHW transpose, one kernel.
// Each block computes scale/shift for its TC channels in LDS, then processes
// a 64-row x TC tile: bf16 CL in-place update + fp32 NCDHW store.
// Grid (Mrows/64, C/TC), TC <= 64.
// ---------------------------------------------------------------------------
__global__ __launch_bounds__(256) void bn_apply_t(
    unsigned short* __restrict__ x, const float* __restrict__ sums,
    const float* __restrict__ g, const float* __restrict__ bt,
    float* __restrict__ outN, int C, int TC, int S, float invcnt)
{
    __shared__ __align__(16) float T[64][68];
    __shared__ float scs[64], shs[64];
    const int tid = threadIdx.x;
    const long m0 = (long)blockIdx.x * 64;
    const int c0 = blockIdx.y * TC;
    if (tid < TC) {
        int c = c0 + tid;
        float mean = sums[c] * invcnt;
        float var = sums[C + c] * invcnt - mean * mean;
        float rs = rsqrtf(var + 1e-5f);
        float scl = g[c] * rs;
        scs[tid] = scl;
        shs[tid] = bt[c] - mean * scl;
    }
    __syncthreads();
    const int spr = TC >> 3;
    const int lg = (spr == 8) ? 3 : 2;
    const int tot = 64 * spr;
    for (int u = tid; u < tot; u += 256) {
        int r = u >> lg, sl = u & (spr - 1);
        size_t idx = (size_t)(m0 + r) * C + c0 + sl * 8;
        uint4 v = *(uint4*)&x[idx];
        unsigned short* pv = (unsigned short*)&v;
#pragma unroll
        for (int j = 0; j < 8; ++j) {
            int cl = sl * 8 + j;
            float f = b2f(pv[j]);
            f = lrelu_f(f * scs[cl] + shs[cl]);
            pv[j] = f2b(f);
            T[cl][r] = f;
        }
        *(uint4*)&x[idx] = v;
    }
    __syncthreads();
    const int tpc = 256 / TC;
    const int rpt = 64 / tpc;
    int cl = tid / tpc;
    int r0 = (tid % tpc) * rpt;
    int c = c0 + cl;
    if ((S & 63) == 0) {
        long b = m0 / S;
        long s0 = m0 - b * S;
        float* op = outN + ((size_t)b * C + c) * S + s0 + r0;
        for (int r = 0; r < rpt; r += 4)
            *(float4*)(op + r) = *(float4*)&T[cl][r0 + r];
    } else {
        for (int r = 0; r < rpt; ++r) {
            long m = m0 + r0 + r;
            long b = m / S, s = m - b * S;
            outN[((size_t)b * C + c) * S + s] = T[cl][r0 + r];
        }
    }
}

// ---------------------------------------------------------------------------
// Deformable trilinear sampling.
// ---------------------------------------------------------------------------
__global__ __launch_bounds__(256) void deform_val(
    const unsigned short* __restrict__ xcl, const float* __restrict__ offc,
    unsigned short* __restrict__ val)
{
    int bs = blockIdx.x;
    int b = bs >> 5, s = bs & 31;
    int od = s >> 4, oh = (s >> 2) & 3, ow = s & 3;
    __shared__ float cw[64][8];
    __shared__ int cidx[64][8];
    int tid = threadIdx.x;
    if (tid < 64) {
        int gk = tid, k = gk & 15;
        int ky = k >> 2, kx = k & 3;
        const float* op = offc + (size_t)bs * 192 + gk * 3;
        float pz = op[0] + (float)od;
        float py = op[1] + (float)(oh * 2 - 1 + ky);
        float px = op[2] + (float)(ow * 2 - 1 + kx);
        float z0 = floorf(pz), y0 = floorf(py), x0 = floorf(px);
        float fz = pz - z0, fy = py - y0, fx = px - x0;
#pragma unroll
        for (int ci = 0; ci < 8; ++ci) {
            int cz = ci >> 2, cy = (ci >> 1) & 1, cx = ci & 1;
            float zc = z0 + cz, yc = y0 + cy, xc = x0 + cx;
            bool ok = zc >= 0.f && zc <= 1.f && yc >= 0.f && yc <= 7.f && xc >= 0.f && xc <= 7.f;
            int zi = min(max((int)zc, 0), 1);
            int yi = min(max((int)yc, 0), 7);
            int xi = min(max((int)xc, 0), 7);
            float wz = cz ? fz : 1.f - fz;
            float wy = cy ? fy : 1.f - fy;
            float wx = cx ? fx : 1.f - fx;
            cw[gk][ci] = ok ? wz * wy * wx : 0.f;
            cidx[gk][ci] = (zi * 8 + yi) * 8 + xi;
        }
    }
    __syncthreads();
    const unsigned short* xb = xcl + (size_t)b * 128 * 256;
    unsigned short* vo = val + (size_t)bs * 4096;
    for (int j = tid; j < 4096; j += 256) {
        int c = j & 255, tap = j >> 8;
        int gk = ((c >> 6) << 4) | tap;
        float v = 0.f;
#pragma unroll
        for (int i = 0; i < 8; ++i)
            v += cw[gk][i] * b2f(xb[(size_t)cidx[gk][i] * 256 + c]);
        vo[j] = f2b(v);
    }
}

// ---------------------------------------------------------------------------
extern "C" void kernel_launch(void* const* d_in, const int* in_sizes, int n_in,
                              void* d_out, int out_size, void* d_ws, size_t ws_size,
                              hipStream_t stream)
{
    (void)in_sizes; (void)n_in; (void)out_size; (void)ws_size;
    const float* x     = (const float*)d_in[0];
    const float* w1    = (const float*)d_in[1];
    const float* w2    = (const float*)d_in[2];
    const float* w3    = (const float*)d_in[3];
    const float* w4    = (const float*)d_in[4];
    const float* w_off = (const float*)d_in[5];
    const float* w5    = (const float*)d_in[6];
    const float* w6    = (const float*)d_in[7];
    const float* g2 = (const float*)d_in[8];  const float* b2 = (const float*)d_in[9];
    const float* g3 = (const float*)d_in[10]; const float* b3 = (const float*)d_in[11];
    const float* g4 = (const float*)d_in[12]; const float* b4 = (const float*)d_in[13];
    const float* g5 = (const float*)d_in[14]; const float* b5 = (const float*)d_in[15];
    const float* g6 = (const float*)d_in[16]; const float* b6 = (const float*)d_in[17];

    float* out = (float*)d_out;
    float* enc0 = out;
    float* enc1 = out + 33554432;
    float* enc2 = out + 46137344;
    float* enc3 = out + 50331648;
    float* enc4 = out + 52428800;
    float* enc5 = out + 53477376;

    // workspace layout (~150.5 MiB)
    char* W = (char*)d_ws;
    unsigned short* wpk  = (unsigned short*)(W + 0);
    unsigned short* w1p  = (unsigned short*)(W + 0);
    unsigned short* w2p  = (unsigned short*)(W + 16384);
    unsigned short* w3p  = (unsigned short*)(W + 147456);
    unsigned short* w4p  = (unsigned short*)(W + 671744);
    unsigned short* wofp = (unsigned short*)(W + 1720320);
    unsigned short* w5p  = (unsigned short*)(W + 3293184);
    unsigned short* w6p  = (unsigned short*)(W + 7487488);
    unsigned short* xcl  = (unsigned short*)(W + 17457152);   // dies after conv1
    unsigned short* e1c  = (unsigned short*)(W + 17457152);   // reuses xcl region
    unsigned short* e2c  = (unsigned short*)(W + 42622976);
    unsigned short* e3c  = (unsigned short*)(W + 51011584);
    unsigned short* e0c  = (unsigned short*)(W + 84566016);   // dies after conv2
    unsigned short* valb = (unsigned short*)(W + 84566016);   // reuses e0c region
    unsigned short* e4c  = (unsigned short*)(W + 105537536);
    unsigned short* e5c  = (unsigned short*)(W + 107896832);
    // contiguous zero-init tail (single memset): offc | raw5 | raw6 | sums
    char* Z = W + 151674880;
    float* offc = (float*)(Z);                 // 1572864 B  fp32 [2048][192]
    float* raw5 = (float*)(Z + 1572864);       // 4194304 B  fp32 [2048][512]
    float* raw6 = (float*)(Z + 5767168);       // 262144 B   fp32 [128][512]
    float* sums = (float*)(Z + 6029312);       // 24576 B: 6 slices x 1024 fl
    float* sums2 = sums + 1024;
    float* sums3 = sums + 2048;
    float* sums4 = sums + 3072;
    float* sums5 = sums + 4096;

    // ---- prep: single memset for all zero-init buffers; input+weight repack
    hipMemsetAsync(Z, 0, 6053888, stream);
    prep_k<<<162080, 256, 0, stream>>>(x, xcl, w1, w2, w3, w4, w_off, w5, w6, wpk);

    // ---- L1: conv1 (4x4x4 s2 p1), lrelu fused -> e0c + enc0 NCDHW (EPI5)
    igemm<256, 32, 2, 5><<<dim3(4096, 1, 1), 512, 0, stream>>>(
        xcl, w1p, e0c, enc0, 1048576, 32, 256, 256,
        4, 8, 128, 128, 4, 4, 4, 2, 2, 2, 1, 1, 1, 4, 64, 64);

    // ---- L2 (EPI4: sums fused into epilogue)
    igemm<256, 64, 1, 4><<<dim3(768, 1, 1), 512, 0, stream>>>(
        e0c, w2p, e1c, sums, 196608, 64, 1024, 1024,
        32, 4, 64, 64, 2, 4, 4, 1, 2, 2, 0, 1, 1, 3, 32, 32);
    bn_apply_t<<<dim3(3072, 1), 256, 0, stream>>>(e1c, sums, g2, b2, enc1, 64, 64, 3072, 1.f / 196608.f);

    // ---- L3
    igemm<256, 64, 1, 4><<<dim3(128, 2), 512, 0, stream>>>(
        e1c, w3p, e2c, sums2, 32768, 128, 2048, 2048,
        64, 3, 32, 32, 2, 4, 4, 1, 2, 2, 0, 1, 1, 2, 16, 16);
    bn_apply_t<<<dim3(512, 2), 256, 0, stream>>>(e2c, sums2, g3, b3, enc2, 128, 64, 512, 1.f / 32768.f);

    // ---- L4
    igemm<128, 64, 1, 4><<<dim3(64, 4), 256, 0, stream>>>(
        e2c, w4p, e3c, sums3, 8192, 256, 2048, 2048,
        128, 2, 16, 16, 1, 4, 4, 1, 2, 2, 0, 1, 1, 2, 8, 8);
    bn_apply_t<<<dim3(128, 4), 256, 0, stream>>>(e3c, sums3, g4, b4, enc3, 256, 64, 128, 1.f / 8192.f);

    // ---- offset conv (no BN/act), split-K 8 atomic into pre-zeroed fp32 CL
    igemm<128, 64, 1, 2><<<dim3(16, 3, 8), 256, 0, stream>>>(
        e3c, wofp, offc, nullptr, 2048, 192, 4096, 512,
        256, 2, 8, 8, 1, 4, 4, 1, 2, 2, 0, 1, 1, 2, 4, 4);

    // ---- deformable sampling + GEMM (split-K 8, fp32 atomic)
    deform_val<<<2048, 256, 0, stream>>>(e3c, offc, valb);
    igemm<128, 64, 0, 2><<<dim3(16, 8, 8), 256, 0, stream>>>(
        valb, w5p, raw5, nullptr, 2048, 512, 4096, 512,
        0, 0, 0, 0, 1, 1, 1, 1, 1, 1, 0, 0, 0, 1, 1, 1);
    f2b_sums<<<256, 256, 0, stream>>>(raw5, e4c, sums4, 131072L, 512);
    bn_apply_t<<<dim3(32, 8), 256, 0, stream>>>(e4c, sums4, g5, b5, enc4, 512, 64, 32, 1.f / 2048.f);

    // ---- L6: plain GEMM on CL enc4 (split-K 32)
    igemm<128, 64, 0, 2><<<dim3(1, 8, 32), 256, 0, stream>>>(
        e4c, w6p, raw6, nullptr, 128, 512, 8192, 256,
        0, 0, 0, 0, 1, 1, 1, 1, 1, 1, 0, 0, 0, 1, 1, 1);
    f2b_sums<<<32, 256, 0, stream>>>(raw6, e5c, sums5, 8192L, 512);
    bn_apply_t<<<dim3(2, 8), 256, 0, stream>>>(e5c, sums5, g6, b6, enc5, 512, 64, 2, 1.f / 128.f);
}

// Round 12
// 531.860 us; speedup vs baseline: 1.0244x; 1.0244x over previous
//
#include <hip/hip_runtime.h>
#include <hip/hip_bf16.h>
#include <cstdint>

typedef short bf16x8 __attribute__((ext_vector_type(8)));
typedef float f32x4 __attribute__((ext_vector_type(4)));

__device__ __forceinline__ float lrelu_f(float y) { return y >= 0.f ? y : 0.2f * y; }
__device__ __forceinline__ float b2f(unsigned short u) {
    union { unsigned int i; float f; } v; v.i = ((unsigned int)u) << 16; return v.f;
}
__device__ __forceinline__ unsigned short f2b(float f) {
    union { unsigned int i; float f; } v; v.f = f;
    unsigned int r = v.i + 0x7FFFu + ((v.i >> 16) & 1u);
    return (unsigned short)(r >> 16);
}

// ---------------------------------------------------------------------------
// Fused prep: input NCDHW->CL bf16 repack (blocks 0..131071) + all-weight
// repack (blocks 131072..162079).
// ---------------------------------------------------------------------------
__global__ __launch_bounds__(256) void prep_k(
    const float* __restrict__ x, unsigned short* __restrict__ xc,
    const float* __restrict__ w1, const float* __restrict__ w2,
    const float* __restrict__ w3, const float* __restrict__ w4,
    const float* __restrict__ w_off, const float* __restrict__ w5,
    const float* __restrict__ w6, unsigned short* __restrict__ wp)
{
    int bid = blockIdx.x;
    if (bid < 131072) {
        int i = bid * 256 + threadIdx.x;      // 33554432 threads
        int c = i & 3, w = (i >> 2) & 127, h = (i >> 9) & 127, d = (i >> 16) & 7, b = i >> 19;
        float v = (c < 3) ? x[(((size_t)b * 3 + c) * 8 + d) * 16384 + h * 128 + w] : 0.f;
        xc[i] = f2b(v);
        return;
    }
    long i = (long)(bid - 131072) * 256 + threadIdx.x;   // 7,938,048 threads
    const float* src; int Cin, Tap, Cip; long rel;
    if (i < 8192)         { src = w1;    Cin = 3;   Tap = 64; Cip = 4;   rel = i; }
    else if (i < 73728)   { src = w2;    Cin = 32;  Tap = 32; Cip = 32;  rel = i - 8192; }
    else if (i < 335872)  { src = w3;    Cin = 64;  Tap = 32; Cip = 64;  rel = i - 73728; }
    else if (i < 860160)  { src = w4;    Cin = 128; Tap = 16; Cip = 128; rel = i - 335872; }
    else if (i < 1646592) { src = w_off; Cin = 256; Tap = 16; Cip = 256; rel = i - 860160; }
    else if (i < 3743744) { src = w5;    Cin = 256; Tap = 16; Cip = 256; rel = i - 1646592; }
    else                  { src = w6;    Cin = 512; Tap = 16; Cip = 512; rel = i - 3743744; }
    int c = (int)(rel % Cip);
    long t1 = rel / Cip;
    int t = (int)(t1 % Tap);
    long o = t1 / Tap;
    wp[i] = (c < Cin) ? f2b(src[((size_t)o * Cin + c) * Tap + t]) : (unsigned short)0;
}

// ---------------------------------------------------------------------------
// Implicit-GEMM MFMA kernel. C[M][N] = A[M][K] * Bw[N][K]^T, bf16 in, fp32 acc.
// Tile TM x BN (threads = TM*2), K-step 64 (two 32-chunks per barrier pair).
// Simple stage->sync->MFMA->sync loop: measured best (r7/r10); r8 (LDS dbuf)
// hit the occupancy cliff, r9 (reg-staged) spilled to scratch; r11's XCD
// swizzle cost ~15us (all operands L3-fit). Keep it plain.
// AMODE 0: plain row-major bf16 [M][K]
// AMODE 1: CL im2col, K order [tap][c], Ci%32==0, masked borders; split-K ok
// AMODE 2: conv1: 4x4x4, Cip=4, K order [tap][c4], masked
// EPI 0: bf16; EPI 1: fp32; EPI 2: fp32 atomicAdd; EPI 3: lrelu+bf16;
// EPI 4: bf16 + per-channel sum/sumsq; EPI 5: lrelu+bf16 + fp32 NCDHW float4
// ---------------------------------------------------------------------------
template<int TM, int BN, int AMODE, int EPI>
__global__ __launch_bounds__(TM * 2) void igemm(
    const unsigned short* __restrict__ A, const unsigned short* __restrict__ Bw,
    void* __restrict__ Cout, float* __restrict__ sums,
    int M, int N, int K, int klen,
    int Ci, int Di, int Hi, int Wi,
    int kd, int kh, int kw,
    int sd, int sh_, int sw_, int pd, int ph_, int pw_,
    int Do, int Ho, int Wo)
{
    constexpr int NT = TM * 2;
    constexpr int NF = BN / 32;
    constexpr int WN = 16 * NF;
    constexpr int NBU = (BN * 4 + NT - 1) / NT;
    constexpr int NAU = (AMODE == 2) ? 4 : 2;
    constexpr int AH = 4 * TM * 8;         // shorts per As k-chunk buffer
    constexpr int BH = 4 * BN * 8;
    __shared__ __align__(16) unsigned short As[2][4][TM][8];
    __shared__ __align__(16) unsigned short Bs[2][4][BN][8];
    __shared__ float redbuf[(EPI == 4) ? 2 * BN : 1];
    const int tid = threadIdx.x;
    const int m0 = blockIdx.x * TM;
    const int n0 = blockIdx.y * BN;
    const int k0 = blockIdx.z * klen;
    const int kend = min(K, k0 + klen);
    unsigned short* const As0 = &As[0][0][0][0];
    unsigned short* const Bs0 = &Bs[0][0][0][0];

    // B staging precompute
    size_t bsrc[NBU];
    int boff[NBU];
#pragma unroll
    for (int i = 0; i < NBU; ++i) {
        int u = tid + i * NT;
        int row = u >> 2, s = u & 3;
        if (BN * 4 >= NT || u < BN * 4) {
            bsrc[i] = (size_t)(n0 + row) * K + s * 8;
            boff[i] = (s * BN + row) * 8;
        }
    }

    // A staging precompute
    size_t asz[2];
    int asrc[NAU];
    unsigned long long amask[NAU];
    int aoff[NAU];

    if constexpr (AMODE == 0) {
#pragma unroll
        for (int i = 0; i < 2; ++i) {
            int u = tid + i * NT;
            int r = u >> 2, s = u & 3;
            asz[i] = (size_t)(m0 + r) * K + s * 8;
            aoff[i] = (s * TM + r) * 8;
        }
    } else {
#pragma unroll
        for (int i = 0; i < NAU; ++i) {
            int u = tid + i * NT;
            int r = (AMODE == 2) ? (u >> 3) : (u >> 2);
            int m = m0 + r;
            int ow = m % Wo; int t1 = m / Wo;
            int oh = t1 % Ho; t1 /= Ho;
            int od = t1 % Do; int b = t1 / Do;
            int id0 = od * sd - pd, ih0 = oh * sh_ - ph_, iw0 = ow * sw_ - pw_;
            unsigned long long xm = 0ull, yx = 0ull, mask = 0ull;
            for (int p = 0; p < kw; ++p) if ((unsigned)(iw0 + p) < (unsigned)Wi) xm |= 1ull << p;
            for (int p = 0; p < kh; ++p) if ((unsigned)(ih0 + p) < (unsigned)Hi) yx |= xm << (p * kw);
            for (int p = 0; p < kd; ++p) if ((unsigned)(id0 + p) < (unsigned)Di) mask |= yx << (p * kh * kw);
            amask[i] = mask;
            int bsp = ((b * Di + id0) * Hi + ih0) * Wi + iw0;
            if constexpr (AMODE == 1) {
                int s = u & 3;
                asrc[i] = bsp * Ci + s * 8;
                aoff[i] = (s * TM + r) * 8;
            } else {
                int j = u & 7;
                asrc[i] = (bsp + (j >> 2) * Wi + (j & 3)) * 4;
                aoff[i] = ((j >> 1) * TM + r) * 8 + (j & 1) * 4;
            }
        }
    }

    f32x4 acc[4][NF];
#pragma unroll
    for (int i = 0; i < 4; ++i)
#pragma unroll
        for (int j = 0; j < NF; ++j) acc[i][j] = (f32x4){0.f, 0.f, 0.f, 0.f};

    const int lane = tid & 63, wv = tid >> 6;
    const int wm = wv >> 1, wn = wv & 1;
    const int kg = lane >> 4, fr = lane & 15;

    // uniform k-walk state (AMODE 1), initialized from k0 for split-K
    int c0 = 0, kx = 0, ky = 0, tap = 0, doff = 0;
    if constexpr (AMODE == 1) {
        c0 = k0 % Ci;
        tap = k0 / Ci;
        kx = tap % kw;
        int t2 = tap / kw;
        ky = t2 % kh;
        int kz = t2 / kh;
        doff = (kz * Hi + ky) * Wi + kx;
    }
    auto advance = [&]() {
        c0 += 32;
        if (c0 >= Ci) {
            c0 = 0; ++tap; ++kx; ++doff;
            if (kx == kw) {
                kx = 0; doff += Wi - kw; ++ky;
                if (ky == kh) { ky = 0; doff += (Hi - kh) * Wi; }
            }
        }
    };

    for (int k = k0; k < kend; k += 64) {
        // ---- B stage (two chunks)
#pragma unroll
        for (int i = 0; i < NBU; ++i)
            if (BN * 4 >= NT || tid + i * NT < BN * 4) {
                uint4 v0 = *(const uint4*)&Bw[bsrc[i] + k];
                uint4 v1 = *(const uint4*)&Bw[bsrc[i] + k + 32];
                *(uint4*)(Bs0 + boff[i]) = v0;
                *(uint4*)(Bs0 + BH + boff[i]) = v1;
            }
        // ---- A stage (two chunks)
        if constexpr (AMODE == 0) {
#pragma unroll
            for (int i = 0; i < 2; ++i) {
                uint4 v0 = *(const uint4*)&A[asz[i] + k];
                uint4 v1 = *(const uint4*)&A[asz[i] + k + 32];
                *(uint4*)(As0 + aoff[i]) = v0;
                *(uint4*)(As0 + AH + aoff[i]) = v1;
            }
        } else if constexpr (AMODE == 1) {
            int t0 = tap, d0 = doff * Ci + c0;
            advance();
            int t1 = tap, d1 = doff * Ci + c0;
            advance();
#pragma unroll
            for (int i = 0; i < 2; ++i) {
                uint4 v0 = {0u, 0u, 0u, 0u}, v1 = {0u, 0u, 0u, 0u};
                if ((amask[i] >> t0) & 1ull) v0 = *(const uint4*)&A[(size_t)(asrc[i] + d0)];
                if ((amask[i] >> t1) & 1ull) v1 = *(const uint4*)&A[(size_t)(asrc[i] + d1)];
                *(uint4*)(As0 + aoff[i]) = v0;
                *(uint4*)(As0 + AH + aoff[i]) = v1;
            }
        } else {
            int kz = k >> 6;
            int U0 = kz * (Hi * Wi) * 4;
            int U1 = U0 + 2 * Wi * 4;
            int tap0 = k >> 2;
#pragma unroll
            for (int i = 0; i < 4; ++i) {
                int j = (tid + i * NT) & 7;
                uint2 v0 = {0u, 0u}, v1 = {0u, 0u};
                if ((amask[i] >> (tap0 + j)) & 1ull)
                    v0 = *(const uint2*)&A[(size_t)(asrc[i] + U0)];
                if ((amask[i] >> (tap0 + 8 + j)) & 1ull)
                    v1 = *(const uint2*)&A[(size_t)(asrc[i] + U1)];
                *(uint2*)(As0 + aoff[i]) = v0;
                *(uint2*)(As0 + AH + aoff[i]) = v1;
            }
        }
        __syncthreads();
#pragma unroll
        for (int kb = 0; kb < 2; ++kb) {
            bf16x8 af[4], bfr[NF];
#pragma unroll
            for (int mi = 0; mi < 4; ++mi)
                af[mi] = *(const bf16x8*)&As[kb][kg][wm * 64 + mi * 16 + fr][0];
#pragma unroll
            for (int ni = 0; ni < NF; ++ni)
                bfr[ni] = *(const bf16x8*)&Bs[kb][kg][wn * WN + ni * 16 + fr][0];
#pragma unroll
            for (int mi = 0; mi < 4; ++mi)
#pragma unroll
                for (int ni = 0; ni < NF; ++ni)
                    acc[mi][ni] = __builtin_amdgcn_mfma_f32_16x16x32_bf16(af[mi], bfr[ni], acc[mi][ni], 0, 0, 0);
        }
        __syncthreads();
    }

    // ---- epilogue: D row=(lane>>4)*4+reg, col=lane&15
    if constexpr (EPI == 4) {
        for (int j = tid; j < 2 * BN; j += NT) redbuf[j] = 0.f;
        __syncthreads();
    }
    const int rb = m0 + wm * 64 + (lane >> 4) * 4;
    const int cb = n0 + wn * WN + fr;
    float p1[NF], p2[NF];
    if constexpr (EPI == 4) {
#pragma unroll
        for (int ni = 0; ni < NF; ++ni) { p1[ni] = 0.f; p2[ni] = 0.f; }
    }
#pragma unroll
    for (int mi = 0; mi < 4; ++mi)
#pragma unroll
        for (int rg = 0; rg < 4; ++rg) {
            size_t rowbase = (size_t)(rb + mi * 16 + rg) * N;
#pragma unroll
            for (int ni = 0; ni < NF; ++ni) {
                size_t idx = rowbase + cb + ni * 16;
                float vv = acc[mi][ni][rg];
                if constexpr (EPI == 0) ((unsigned short*)Cout)[idx] = f2b(vv);
                else if constexpr (EPI == 1) ((float*)Cout)[idx] = vv;
                else if constexpr (EPI == 2) atomicAdd((float*)Cout + idx, vv);
                else if constexpr (EPI == 3 || EPI == 5) ((unsigned short*)Cout)[idx] = f2b(lrelu_f(vv));
                else {
                    ((unsigned short*)Cout)[idx] = f2b(vv);
                    p1[ni] += vv; p2[ni] += vv * vv;
                }
            }
        }
    if constexpr (EPI == 4) {
#pragma unroll
        for (int ni = 0; ni < NF; ++ni) {
            int cl = wn * WN + ni * 16 + fr;
            atomicAdd(&redbuf[cl], p1[ni]);
            atomicAdd(&redbuf[BN + cl], p2[ni]);
        }
        __syncthreads();
        for (int j = tid; j < 2 * BN; j += NT) {
            int gcol = (j < BN) ? (n0 + j) : (N + n0 + j - BN);
            atomicAdd(&sums[gcol], redbuf[j]);
        }
    }
    if constexpr (EPI == 5) {
        // direct fp32 NCDHW store (conv1 geometry: C=32, S=16384)
#pragma unroll
        for (int mi = 0; mi < 4; ++mi) {
            int mr = rb + mi * 16;
            int b = mr >> 14, ssp = mr & 16383;
            float4 f;
            f.x = lrelu_f(acc[mi][0][0]);
            f.y = lrelu_f(acc[mi][0][1]);
            f.z = lrelu_f(acc[mi][0][2]);
            f.w = lrelu_f(acc[mi][0][3]);
            *(float4*)&sums[((size_t)(b * 32 + cb)) * 16384 + ssp] = f;
        }
    }
}

// ---------------------------------------------------------------------------
// Fused fp32->bf16 convert + BN partial sums (for split-K fp32 outputs).
// ---------------------------------------------------------------------------
__global__ __launch_bounds__(256) void f2b_sums(const float* __restrict__ in,
                                                unsigned short* __restrict__ o,
                                                float* __restrict__ sums,
                                                long totalSlots, int C)
{
    const int tid = threadIdx.x;
    long gid = (long)blockIdx.x * 256 + tid;
    long stride = (long)gridDim.x * 256;     // stride*8 % C == 0 required
    float s1[8], s2[8];
#pragma unroll
    for (int j = 0; j < 8; ++j) { s1[j] = 0.f; s2[j] = 0.f; }
    for (long s = gid; s < totalSlots; s += stride) {
        float4 a = *(const float4*)&in[s * 8];
        float4 b = *(const float4*)&in[s * 8 + 4];
        float f[8] = {a.x, a.y, a.z, a.w, b.x, b.y, b.z, b.w};
        unsigned short u[8];
#pragma unroll
        for (int j = 0; j < 8; ++j) { u[j] = f2b(f[j]); s1[j] += f[j]; s2[j] += f[j] * f[j]; }
        *(uint4*)&o[s * 8] = *(uint4*)u;
    }
    __shared__ float r1[2048], r2[2048];
#pragma unroll
    for (int j = 0; j < 8; ++j) { r1[tid * 8 + j] = s1[j]; r2[tid * 8 + j] = s2[j]; }
    __syncthreads();
    int G = C >> 3;
    for (int c = tid; c < C; c += 256) {
        int grp = c >> 3, j = c & 7;
        float a = 0.f, b = 0.f;
        for (int th = grp; th < 256; th += G) { a += r1[th * 8 + j]; b += r2[th * 8 + j]; }
        atomicAdd(&sums[c], a);
        atomicAdd(&sums[C + c], b);
    }
}

// ---------------------------------------------------------------------------
// BN finalize (from sums slice) + apply + lrelu + NCDHW transpose, one kernel.
// Each block computes scale/shift for its TC channels in LDS, then processes
// a 64-row x TC tile: bf16 CL in-place update + fp32 NCDHW store.
// Grid (Mrows/64, C/TC), TC <= 64.
// ---------------------------------------------------------------------------
__global__ __launch_bounds__(256) void bn_apply_t(
    unsigned short* __restrict__ x, const float* __restrict__ sums,
    const float* __restrict__ g, const float* __restrict__ bt,
    float* __restrict__ outN, int C, int TC, int S, float invcnt)
{
    __shared__ __align__(16) float T[64][68];
    __shared__ float scs[64], shs[64];
    const int tid = threadIdx.x;
    const long m0 = (long)blockIdx.x * 64;
    const int c0 = blockIdx.y * TC;
    if (tid < TC) {
        int c = c0 + tid;
        float mean = sums[c] * invcnt;
        float var = sums[C + c] * invcnt - mean * mean;
        float rs = rsqrtf(var + 1e-5f);
        float scl = g[c] * rs;
        scs[tid] = scl;
        shs[tid] = bt[c] - mean * scl;
    }
    __syncthreads();
    const int spr = TC >> 3;
    const int lg = (spr == 8) ? 3 : 2;
    const int tot = 64 * spr;
    for (int u = tid; u < tot; u += 256) {
        int r = u >> lg, sl = u & (spr - 1);
        size_t idx = (size_t)(m0 + r) * C + c0 + sl * 8;
        uint4 v = *(uint4*)&x[idx];
        unsigned short* pv = (unsigned short*)&v;
#pragma unroll
        for (int j = 0; j < 8; ++j) {
            int cl = sl * 8 + j;
            float f = b2f(pv[j]);
            f = lrelu_f(f * scs[cl] + shs[cl]);
            pv[j] = f2b(f);
            T[cl][r] = f;
        }
        *(uint4*)&x[idx] = v;
    }
    __syncthreads();
    const int tpc = 256 / TC;
    const int rpt = 64 / tpc;
    int cl = tid / tpc;
    int r0 = (tid % tpc) * rpt;
    int c = c0 + cl;
    if ((S & 63) == 0) {
        long b = m0 / S;
        long s0 = m0 - b * S;
        float* op = outN + ((size_t)b * C + c) * S + s0 + r0;
        for (int r = 0; r < rpt; r += 4)
            *(float4*)(op + r) = *(float4*)&T[cl][r0 + r];
    } else {
        for (int r = 0; r < rpt; ++r) {
            long m = m0 + r0 + r;
            long b = m / S, s = m - b * S;
            outN[((size_t)b * C + c) * S + s] = T[cl][r0 + r];
        }
    }
}

// ---------------------------------------------------------------------------
// Deformable trilinear sampling.
// ---------------------------------------------------------------------------
__global__ __launch_bounds__(256) void deform_val(
    const unsigned short* __restrict__ xcl, const float* __restrict__ offc,
    unsigned short* __restrict__ val)
{
    int bs = blockIdx.x;
    int b = bs >> 5, s = bs & 31;
    int od = s >> 4, oh = (s >> 2) & 3, ow = s & 3;
    __shared__ float cw[64][8];
    __shared__ int cidx[64][8];
    int tid = threadIdx.x;
    if (tid < 64) {
        int gk = tid, k = gk & 15;
        int ky = k >> 2, kx = k & 3;
        const float* op = offc + (size_t)bs * 192 + gk * 3;
        float pz = op[0] + (float)od;
        float py = op[1] + (float)(oh * 2 - 1 + ky);
        float px = op[2] + (float)(ow * 2 - 1 + kx);
        float z0 = floorf(pz), y0 = floorf(py), x0 = floorf(px);
        float fz = pz - z0, fy = py - y0, fx = px - x0;
#pragma unroll
        for (int ci = 0; ci < 8; ++ci) {
            int cz = ci >> 2, cy = (ci >> 1) & 1, cx = ci & 1;
            float zc = z0 + cz, yc = y0 + cy, xc = x0 + cx;
            bool ok = zc >= 0.f && zc <= 1.f && yc >= 0.f && yc <= 7.f && xc >= 0.f && xc <= 7.f;
            int zi = min(max((int)zc, 0), 1);
            int yi = min(max((int)yc, 0), 7);
            int xi = min(max((int)xc, 0), 7);
            float wz = cz ? fz : 1.f - fz;
            float wy = cy ? fy : 1.f - fy;
            float wx = cx ? fx : 1.f - fx;
            cw[gk][ci] = ok ? wz * wy * wx : 0.f;
            cidx[gk][ci] = (zi * 8 + yi) * 8 + xi;
        }
    }
    __syncthreads();
    const unsigned short* xb = xcl + (size_t)b * 128 * 256;
    unsigned short* vo = val + (size_t)bs * 4096;
    for (int j = tid; j < 4096; j += 256) {
        int c = j & 255, tap = j >> 8;
        int gk = ((c >> 6) << 4) | tap;
        float v = 0.f;
#pragma unroll
        for (int i = 0; i < 8; ++i)
            v += cw[gk][i] * b2f(xb[(size_t)cidx[gk][i] * 256 + c]);
        vo[j] = f2b(v);
    }
}

// ---------------------------------------------------------------------------
extern "C" void kernel_launch(void* const* d_in, const int* in_sizes, int n_in,
                              void* d_out, int out_size, void* d_ws, size_t ws_size,
                              hipStream_t stream)
{
    (void)in_sizes; (void)n_in; (void)out_size; (void)ws_size;
    const float* x     = (const float*)d_in[0];
    const float* w1    = (const float*)d_in[1];
    const float* w2    = (const float*)d_in[2];
    const float* w3    = (const float*)d_in[3];
    const float* w4    = (const float*)d_in[4];
    const float* w_off = (const float*)d_in[5];
    const float* w5    = (const float*)d_in[6];
    const float* w6    = (const float*)d_in[7];
    const float* g2 = (const float*)d_in[8];  const float* b2 = (const float*)d_in[9];
    const float* g3 = (const float*)d_in[10]; const float* b3 = (const float*)d_in[11];
    const float* g4 = (const float*)d_in[12]; const float* b4 = (const float*)d_in[13];
    const float* g5 = (const float*)d_in[14]; const float* b5 = (const float*)d_in[15];
    const float* g6 = (const float*)d_in[16]; const float* b6 = (const float*)d_in[17];

    float* out = (float*)d_out;
    float* enc0 = out;
    float* enc1 = out + 33554432;
    float* enc2 = out + 46137344;
    float* enc3 = out + 50331648;
    float* enc4 = out + 52428800;
    float* enc5 = out + 53477376;

    // workspace layout (~150.5 MiB)
    char* W = (char*)d_ws;
    unsigned short* wpk  = (unsigned short*)(W + 0);
    unsigned short* w1p  = (unsigned short*)(W + 0);
    unsigned short* w2p  = (unsigned short*)(W + 16384);
    unsigned short* w3p  = (unsigned short*)(W + 147456);
    unsigned short* w4p  = (unsigned short*)(W + 671744);
    unsigned short* wofp = (unsigned short*)(W + 1720320);
    unsigned short* w5p  = (unsigned short*)(W + 3293184);
    unsigned short* w6p  = (unsigned short*)(W + 7487488);
    unsigned short* xcl  = (unsigned short*)(W + 17457152);   // dies after conv1
    unsigned short* e1c  = (unsigned short*)(W + 17457152);   // reuses xcl region
    unsigned short* e2c  = (unsigned short*)(W + 42622976);
    unsigned short* e3c  = (unsigned short*)(W + 51011584);
    unsigned short* e0c  = (unsigned short*)(W + 84566016);   // dies after conv2
    unsigned short* valb = (unsigned short*)(W + 84566016);   // reuses e0c region
    unsigned short* e4c  = (unsigned short*)(W + 105537536);
    unsigned short* e5c  = (unsigned short*)(W + 107896832);
    // contiguous zero-init tail (single memset): offc | raw5 | raw6 | sums
    char* Z = W + 151674880;
    float* offc = (float*)(Z);                 // 1572864 B  fp32 [2048][192]
    float* raw5 = (float*)(Z + 1572864);       // 4194304 B  fp32 [2048][512]
    float* raw6 = (float*)(Z + 5767168);       // 262144 B   fp32 [128][512]
    float* sums = (float*)(Z + 6029312);       // 24576 B: slices x 1024 fl
    float* sums2 = sums + 1024;
    float* sums3 = sums + 2048;
    float* sums4 = sums + 3072;
    float* sums5 = sums + 4096;

    // ---- prep: single memset for all zero-init buffers; input+weight repack
    hipMemsetAsync(Z, 0, 6053888, stream);
    prep_k<<<162080, 256, 0, stream>>>(x, xcl, w1, w2, w3, w4, w_off, w5, w6, wpk);

    // ---- L1: conv1 (4x4x4 s2 p1), lrelu fused -> e0c + enc0 NCDHW (EPI5)
    igemm<256, 32, 2, 5><<<dim3(4096, 1, 1), 512, 0, stream>>>(
        xcl, w1p, e0c, enc0, 1048576, 32, 256, 256,
        4, 8, 128, 128, 4, 4, 4, 2, 2, 2, 1, 1, 1, 4, 64, 64);

    // ---- L2 (EPI4: sums fused into epilogue)
    igemm<256, 64, 1, 4><<<dim3(768, 1, 1), 512, 0, stream>>>(
        e0c, w2p, e1c, sums, 196608, 64, 1024, 1024,
        32, 4, 64, 64, 2, 4, 4, 1, 2, 2, 0, 1, 1, 3, 32, 32);
    bn_apply_t<<<dim3(3072, 1), 256, 0, stream>>>(e1c, sums, g2, b2, enc1, 64, 64, 3072, 1.f / 196608.f);

    // ---- L3
    igemm<256, 64, 1, 4><<<dim3(128, 2), 512, 0, stream>>>(
        e1c, w3p, e2c, sums2, 32768, 128, 2048, 2048,
        64, 3, 32, 32, 2, 4, 4, 1, 2, 2, 0, 1, 1, 2, 16, 16);
    bn_apply_t<<<dim3(512, 2), 256, 0, stream>>>(e2c, sums2, g3, b3, enc2, 128, 64, 512, 1.f / 32768.f);

    // ---- L4
    igemm<128, 64, 1, 4><<<dim3(64, 4), 256, 0, stream>>>(
        e2c, w4p, e3c, sums3, 8192, 256, 2048, 2048,
        128, 2, 16, 16, 1, 4, 4, 1, 2, 2, 0, 1, 1, 2, 8, 8);
    bn_apply_t<<<dim3(128, 4), 256, 0, stream>>>(e3c, sums3, g4, b4, enc3, 256, 64, 128, 1.f / 8192.f);

    // ---- offset conv (no BN/act), split-K 8 atomic into pre-zeroed fp32 CL
    igemm<128, 64, 1, 2><<<dim3(16, 3, 8), 256, 0, stream>>>(
        e3c, wofp, offc, nullptr, 2048, 192, 4096, 512,
        256, 2, 8, 8, 1, 4, 4, 1, 2, 2, 0, 1, 1, 2, 4, 4);

    // ---- deformable sampling + GEMM (split-K 8, fp32 atomic)
    deform_val<<<2048, 256, 0, stream>>>(e3c, offc, valb);
    igemm<128, 64, 0, 2><<<dim3(16, 8, 8), 256, 0, stream>>>(
        valb, w5p, raw5, nullptr, 2048, 512, 4096, 512,
        0, 0, 0, 0, 1, 1, 1, 1, 1, 1, 0, 0, 0, 1, 1, 1);
    f2b_sums<<<256, 256, 0, stream>>>(raw5, e4c, sums4, 131072L, 512);
    bn_apply_t<<<dim3(32, 8), 256, 0, stream>>>(e4c, sums4, g5, b5, enc4, 512, 64, 32, 1.f / 2048.f);

    // ---- L6: plain GEMM on CL enc4 (split-K 32)
    igemm<128, 64, 0, 2><<<dim3(1, 8, 32), 256, 0, stream>>>(
        e4c, w6p, raw6, nullptr, 128, 512, 8192, 256,
        0, 0, 0, 0, 1, 1, 1, 1, 1, 1, 0, 0, 0, 1, 1, 1);
    f2b_sums<<<32, 256, 0, stream>>>(raw6, e5c, sums5, 8192L, 512);
    bn_apply_t<<<dim3(2, 8), 256, 0, stream>>>(e5c, sums5, g6, b6, enc5, 512, 64, 2, 1.f / 128.f);
}